// Round 2
// baseline (301.674 us; speedup 1.0000x reference)
//
#include <hip/hip_runtime.h>

#define GAMMA 0.7f
static constexpr int K = 8;

// ---------------------------------------------------------------------------
// ws layout (host-computable offsets; counts last so M's value isn't needed):
//   [0, nblocks*K*4)       partials (float)   -- overwritten every call
//   [boff,  boff+nblocks*4) bcounts (int)     -- overwritten every call
//   [doff,  doff+4)         done_ctr (uint)   -- zeroed by count_kernel
//   [coff,  ...)            counts (int, M)   -- run-start stores only;
//                                               absent ids never read
// molecule_id is SORTED -> run boundaries give counts without zero+atomics.
// ---------------------------------------------------------------------------

__global__ void __launch_bounds__(256)
count_kernel(const int* __restrict__ mol, int N,
             int* __restrict__ counts, int* __restrict__ bcounts,
             unsigned* __restrict__ done_ctr) {
    const int t = blockIdx.x * 256 + threadIdx.x;
    if (t == 0) *done_ctr = 0u;  // consumed by main_kernel (next launch)
    const int n0 = t * 4;
    int nb = 0;

    if (n0 + 3 < N) {
        int4 v = *reinterpret_cast<const int4*>(mol + n0);
        int ids[4] = {v.x, v.y, v.z, v.w};
        int prev = (n0 == 0) ? ~ids[0] : mol[n0 - 1];
#pragma unroll
        for (int j = 0; j < 4; ++j) {
            if (ids[j] != prev) {
                ++nb;  // run start
                int lo = n0 + j + 1, hi = N;
                while (lo < hi) {  // first index with mol[idx] != ids[j]
                    int mid = (lo + hi) >> 1;
                    if (mol[mid] == ids[j]) lo = mid + 1; else hi = mid;
                }
                counts[ids[j]] = lo - (n0 + j);
            }
            prev = ids[j];
        }
    } else if (n0 < N) {
        for (int n = n0; n < N; ++n) {
            int id = mol[n];
            int prev = (n == 0) ? ~id : mol[n - 1];
            if (id != prev) {
                ++nb;
                int lo = n + 1, hi = N;
                while (lo < hi) {
                    int mid = (lo + hi) >> 1;
                    if (mol[mid] == id) lo = mid + 1; else hi = mid;
                }
                counts[id] = lo - n;
            }
        }
    }

#pragma unroll
    for (int off = 32; off > 0; off >>= 1) nb += __shfl_down(nb, off, 64);
    __shared__ int bl[4];
    const int wave = threadIdx.x >> 6, lane = threadIdx.x & 63;
    if (lane == 0) bl[wave] = nb;
    __syncthreads();
    if (threadIdx.x == 0)
        bcounts[blockIdx.x] = bl[0] + bl[1] + bl[2] + bl[3];
}

// Each thread: 4 consecutive atoms, float4 loads; deterministic block reduce;
// last-finished block performs the final cross-block reduction (fence+atomic).
__global__ void __launch_bounds__(256)
main_kernel(const float* __restrict__ sx,      // (K, N, 3)
            const float* __restrict__ xt,      // (N, 3)
            const int* __restrict__ mol,       // (N,)
            const int* __restrict__ counts,    // (M,)
            float* __restrict__ partials,      // (nblocks, K)
            const int* __restrict__ bcounts,   // (nblocks,)
            unsigned* __restrict__ done_ctr,
            float* __restrict__ out,
            int N, int nblocks) {
    const int t  = blockIdx.x * 256 + threadIdx.x;
    const int n0 = t * 4;

    float acc[K];
#pragma unroll
    for (int k = 0; k < K; ++k) acc[k] = 0.0f;

    if (n0 + 3 < N) {
        const float4* tp = reinterpret_cast<const float4*>(xt + (size_t)n0 * 3);
        float4 t0 = tp[0], t1 = tp[1], t2 = tp[2];
        float tg[12] = {t0.x, t0.y, t0.z, t0.w, t1.x, t1.y,
                        t1.z, t1.w, t2.x, t2.y, t2.z, t2.w};

        int4 iv = *reinterpret_cast<const int4*>(mol + n0);
        int ids[4] = {iv.x, iv.y, iv.z, iv.w};
        float inv[4];
#pragma unroll
        for (int j = 0; j < 4; ++j)
            inv[j] = 1.0f / (float)counts[ids[j]];

#pragma unroll
        for (int k = 0; k < K; ++k) {
            const float4* sp = reinterpret_cast<const float4*>(
                sx + (size_t)k * N * 3 + (size_t)n0 * 3);
            float4 s0 = sp[0], s1 = sp[1], s2 = sp[2];
            float sv[12] = {s0.x, s0.y, s0.z, s0.w, s1.x, s1.y,
                            s1.z, s1.w, s2.x, s2.y, s2.z, s2.w};
#pragma unroll
            for (int j = 0; j < 4; ++j) {
                float dx = sv[3 * j + 0] - tg[3 * j + 0];
                float dy = sv[3 * j + 1] - tg[3 * j + 1];
                float dz = sv[3 * j + 2] - tg[3 * j + 2];
                acc[k] += (dx * dx + dy * dy + dz * dz) * inv[j];
            }
        }
    } else if (n0 < N) {
        for (int n = n0; n < N; ++n) {
            int id = mol[n];
            float invc = 1.0f / (float)counts[id];
            float tx = xt[(size_t)n * 3 + 0];
            float ty = xt[(size_t)n * 3 + 1];
            float tz = xt[(size_t)n * 3 + 2];
#pragma unroll
            for (int k = 0; k < K; ++k) {
                const float* s = sx + (size_t)k * N * 3 + (size_t)n * 3;
                float dx = s[0] - tx, dy = s[1] - ty, dz = s[2] - tz;
                acc[k] += (dx * dx + dy * dy + dz * dz) * invc;
            }
        }
    }

#pragma unroll
    for (int k = 0; k < K; ++k)
#pragma unroll
        for (int off = 32; off > 0; off >>= 1)
            acc[k] += __shfl_down(acc[k], off, 64);

    __shared__ float lds[4][K];
    const int wave = threadIdx.x >> 6, lane = threadIdx.x & 63;
    if (lane == 0) {
#pragma unroll
        for (int k = 0; k < K; ++k) lds[wave][k] = acc[k];
    }
    __syncthreads();
    if (threadIdx.x < K) {
        int k = threadIdx.x;
        partials[(size_t)blockIdx.x * K + k] =
            lds[0][k] + lds[1][k] + lds[2][k] + lds[3][k];
    }

    // ---- last-block final reduction (order-independent, deterministic) ----
    __threadfence();
    __shared__ unsigned last;
    if (threadIdx.x == 0)
        last = (atomicAdd(done_ctr, 1u) == (unsigned)gridDim.x - 1u) ? 1u : 0u;
    __syncthreads();
    if (!last) return;
    __threadfence();

    int vc = 0;
    for (int i = threadIdx.x; i < nblocks; i += 256) vc += bcounts[i];
#pragma unroll
    for (int off = 32; off > 0; off >>= 1) vc += __shfl_down(vc, off, 64);

    float fac[K];
#pragma unroll
    for (int k = 0; k < K; ++k) fac[k] = 0.0f;
    for (int i = threadIdx.x; i < nblocks; i += 256) {
#pragma unroll
        for (int k = 0; k < K; ++k) fac[k] += partials[(size_t)i * K + k];
    }
#pragma unroll
    for (int k = 0; k < K; ++k)
#pragma unroll
        for (int off = 32; off > 0; off >>= 1)
            fac[k] += __shfl_down(fac[k], off, 64);

    __shared__ int vlds[4];
    __shared__ float plds[4][K];
    if (lane == 0) {
        vlds[wave] = vc;
#pragma unroll
        for (int k = 0; k < K; ++k) plds[wave][k] = fac[k];
    }
    __syncthreads();

    if (threadIdx.x == 0) {
        int V = vlds[0] + vlds[1] + vlds[2] + vlds[3];
        float w[K], wsum = 0.0f, g = 1.0f;
        for (int j = 0; j < K; ++j) {  // w[K-1-j] = GAMMA^j
            w[K - 1 - j] = g;
            wsum += g;
            g *= GAMMA;
        }
        float invV = (V > 0) ? 1.0f / (float)V : 0.0f;
        float res = 0.0f;
#pragma unroll
        for (int k = 0; k < K; ++k) {
            float ps = (plds[0][k] + plds[1][k] + plds[2][k] + plds[3][k]) * invV;
            res += (w[k] / wsum) * ps;
        }
        out[0] = res;
    }
}

extern "C" void kernel_launch(void* const* d_in, const int* in_sizes, int n_in,
                              void* d_out, int out_size, void* d_ws, size_t ws_size,
                              hipStream_t stream) {
    const float* states_x = (const float*)d_in[0];  // (K, N, 3)
    const float* x_target = (const float*)d_in[1];  // (N, 3)
    const int*   mol      = (const int*)d_in[2];    // (N,)

    const int N = in_sizes[2];
    const int threads = (N + 3) / 4;
    const int nblocks = (threads + 255) / 256;

    // ws layout (256B-aligned sections)
    char* ws = (char*)d_ws;
    size_t poff = 0;
    size_t boff = ((poff + (size_t)nblocks * K * 4) + 255) & ~(size_t)255;
    size_t doff = ((boff + (size_t)nblocks * 4) + 255) & ~(size_t)255;
    size_t coff = ((doff + 4) + 255) & ~(size_t)255;

    float*    partials = (float*)(ws + poff);
    int*      bcounts  = (int*)(ws + boff);
    unsigned* done_ctr = (unsigned*)(ws + doff);
    int*      counts   = (int*)(ws + coff);

    count_kernel<<<nblocks, 256, 0, stream>>>(mol, N, counts, bcounts, done_ctr);

    main_kernel<<<nblocks, 256, 0, stream>>>(states_x, x_target, mol, counts,
                                             partials, bcounts, done_ctr,
                                             (float*)d_out, N, nblocks);
}

// Round 6
// 71.533 us; speedup vs baseline: 4.2173x; 4.2173x over previous
//
#include <hip/hip_runtime.h>

#define GAMMA 0.7f
static constexpr int K = 8;

// ---------------------------------------------------------------------------
// ws layout (host-computable offsets; counts last so M's value isn't needed):
//   [0, nblocks*K*4)        partials (float) -- overwritten every call
//   [boff, boff+nblocks*4)  bcounts (int)    -- overwritten every call
//   [coff, ...)             counts (int, M)  -- run-start stores only;
//                                              absent ids never read
// molecule_id is SORTED -> run boundaries give counts with no zeroing pass
// and no atomics. Valid-molecule count V = total number of run boundaries.
// NO device-scope fences anywhere (R2's __threadfence per block was a 4x
// regression: per-XCD L2 writeback/invalidate on every block).
// ---------------------------------------------------------------------------

__global__ void __launch_bounds__(256)
count_kernel(const int* __restrict__ mol, int N,
             int* __restrict__ counts, int* __restrict__ bcounts) {
    const int t = blockIdx.x * 256 + threadIdx.x;
    const int n0 = t * 4;
    int nb = 0;

    if (n0 + 3 < N) {
        int4 v = *reinterpret_cast<const int4*>(mol + n0);
        int ids[4] = {v.x, v.y, v.z, v.w};
        int prev = (n0 == 0) ? ~ids[0] : mol[n0 - 1];
#pragma unroll
        for (int j = 0; j < 4; ++j) {
            if (ids[j] != prev) {
                ++nb;  // run start at n0+j
                int lo = n0 + j + 1, hi = N;
                while (lo < hi) {  // first index with mol[idx] != ids[j]
                    int mid = (lo + hi) >> 1;
                    if (mol[mid] == ids[j]) lo = mid + 1; else hi = mid;
                }
                counts[ids[j]] = lo - (n0 + j);
            }
            prev = ids[j];
        }
    } else if (n0 < N) {
        for (int n = n0; n < N; ++n) {
            int id = mol[n];
            int prev = (n == 0) ? ~id : mol[n - 1];
            if (id != prev) {
                ++nb;
                int lo = n + 1, hi = N;
                while (lo < hi) {
                    int mid = (lo + hi) >> 1;
                    if (mol[mid] == id) lo = mid + 1; else hi = mid;
                }
                counts[id] = lo - n;
            }
        }
    }

#pragma unroll
    for (int off = 32; off > 0; off >>= 1) nb += __shfl_down(nb, off, 64);
    __shared__ int bl[4];
    const int wave = threadIdx.x >> 6, lane = threadIdx.x & 63;
    if (lane == 0) bl[wave] = nb;
    __syncthreads();
    if (threadIdx.x == 0)
        bcounts[blockIdx.x] = bl[0] + bl[1] + bl[2] + bl[3];
}

// Each thread: 4 consecutive atoms, float4-vectorized loads.
// acc[k] += sq(k, atom) / count[mol(atom)], deterministic block reduce,
// per-block partials to ws. No fences, no atomics.
__global__ void __launch_bounds__(256)
main_kernel(const float* __restrict__ sx,      // (K, N, 3)
            const float* __restrict__ xt,      // (N, 3)
            const int* __restrict__ mol,       // (N,)
            const int* __restrict__ counts,    // (M,)
            float* __restrict__ partials,      // (nblocks, K)
            int N) {
    const int t  = blockIdx.x * 256 + threadIdx.x;
    const int n0 = t * 4;

    float acc[K];
#pragma unroll
    for (int k = 0; k < K; ++k) acc[k] = 0.0f;

    if (n0 + 3 < N) {
        const float4* tp = reinterpret_cast<const float4*>(xt + (size_t)n0 * 3);
        float4 t0 = tp[0], t1 = tp[1], t2 = tp[2];
        float tg[12] = {t0.x, t0.y, t0.z, t0.w, t1.x, t1.y,
                        t1.z, t1.w, t2.x, t2.y, t2.z, t2.w};

        int4 iv = *reinterpret_cast<const int4*>(mol + n0);
        int ids[4] = {iv.x, iv.y, iv.z, iv.w};
        float inv[4];
#pragma unroll
        for (int j = 0; j < 4; ++j)
            inv[j] = 1.0f / (float)counts[ids[j]];  // count >= 1 (atom exists)

#pragma unroll
        for (int k = 0; k < K; ++k) {
            const float4* sp = reinterpret_cast<const float4*>(
                sx + (size_t)k * N * 3 + (size_t)n0 * 3);
            float4 s0 = sp[0], s1 = sp[1], s2 = sp[2];
            float sv[12] = {s0.x, s0.y, s0.z, s0.w, s1.x, s1.y,
                            s1.z, s1.w, s2.x, s2.y, s2.z, s2.w};
#pragma unroll
            for (int j = 0; j < 4; ++j) {
                float dx = sv[3 * j + 0] - tg[3 * j + 0];
                float dy = sv[3 * j + 1] - tg[3 * j + 1];
                float dz = sv[3 * j + 2] - tg[3 * j + 2];
                acc[k] += (dx * dx + dy * dy + dz * dz) * inv[j];
            }
        }
    } else if (n0 < N) {
        for (int n = n0; n < N; ++n) {
            int id = mol[n];
            float invc = 1.0f / (float)counts[id];
            float tx = xt[(size_t)n * 3 + 0];
            float ty = xt[(size_t)n * 3 + 1];
            float tz = xt[(size_t)n * 3 + 2];
#pragma unroll
            for (int k = 0; k < K; ++k) {
                const float* s = sx + (size_t)k * N * 3 + (size_t)n * 3;
                float dx = s[0] - tx, dy = s[1] - ty, dz = s[2] - tz;
                acc[k] += (dx * dx + dy * dy + dz * dz) * invc;
            }
        }
    }

#pragma unroll
    for (int k = 0; k < K; ++k)
#pragma unroll
        for (int off = 32; off > 0; off >>= 1)
            acc[k] += __shfl_down(acc[k], off, 64);

    __shared__ float lds[4][K];
    const int wave = threadIdx.x >> 6, lane = threadIdx.x & 63;
    if (lane == 0) {
#pragma unroll
        for (int k = 0; k < K; ++k) lds[wave][k] = acc[k];
    }
    __syncthreads();
    if (threadIdx.x < K) {
        int k = threadIdx.x;
        partials[(size_t)blockIdx.x * K + k] =
            lds[0][k] + lds[1][k] + lds[2][k] + lds[3][k];
    }
}

// One block: reduce per-block partials (nblocks*K floats) and boundary
// counts (nblocks ints). No M-sized scan.
__global__ void __launch_bounds__(256)
final_kernel(const float* __restrict__ partials,
             const int* __restrict__ bcounts, int nblocks,
             float* __restrict__ out) {
    const int t = threadIdx.x;

    int vc = 0;
    for (int i = t; i < nblocks; i += 256) vc += bcounts[i];
#pragma unroll
    for (int off = 32; off > 0; off >>= 1) vc += __shfl_down(vc, off, 64);

    float acc[K];
#pragma unroll
    for (int k = 0; k < K; ++k) acc[k] = 0.0f;
    for (int i = t; i < nblocks; i += 256) {
#pragma unroll
        for (int k = 0; k < K; ++k) acc[k] += partials[(size_t)i * K + k];
    }
#pragma unroll
    for (int k = 0; k < K; ++k)
#pragma unroll
        for (int off = 32; off > 0; off >>= 1)
            acc[k] += __shfl_down(acc[k], off, 64);

    __shared__ int vlds[4];
    __shared__ float plds[4][K];
    const int wave = t >> 6, lane = t & 63;
    if (lane == 0) {
        vlds[wave] = vc;
#pragma unroll
        for (int k = 0; k < K; ++k) plds[wave][k] = acc[k];
    }
    __syncthreads();

    if (t == 0) {
        int V = vlds[0] + vlds[1] + vlds[2] + vlds[3];
        float w[K], wsum = 0.0f, g = 1.0f;
        for (int j = 0; j < K; ++j) {  // w[K-1-j] = GAMMA^j
            w[K - 1 - j] = g;
            wsum += g;
            g *= GAMMA;
        }
        float invV = (V > 0) ? 1.0f / (float)V : 0.0f;
        float res = 0.0f;
#pragma unroll
        for (int k = 0; k < K; ++k) {
            float ps = (plds[0][k] + plds[1][k] + plds[2][k] + plds[3][k]) * invV;
            res += (w[k] / wsum) * ps;
        }
        out[0] = res;
    }
}

extern "C" void kernel_launch(void* const* d_in, const int* in_sizes, int n_in,
                              void* d_out, int out_size, void* d_ws, size_t ws_size,
                              hipStream_t stream) {
    const float* states_x = (const float*)d_in[0];  // (K, N, 3)
    const float* x_target = (const float*)d_in[1];  // (N, 3)
    const int*   mol      = (const int*)d_in[2];    // (N,)

    const int N = in_sizes[2];
    const int threads = (N + 3) / 4;
    const int nblocks = (threads + 255) / 256;

    // ws layout (256B-aligned sections)
    char* ws = (char*)d_ws;
    size_t poff = 0;
    size_t boff = ((poff + (size_t)nblocks * K * 4) + 255) & ~(size_t)255;
    size_t coff = ((boff + (size_t)nblocks * 4) + 255) & ~(size_t)255;

    float* partials = (float*)(ws + poff);
    int*   bcounts  = (int*)(ws + boff);
    int*   counts   = (int*)(ws + coff);

    count_kernel<<<nblocks, 256, 0, stream>>>(mol, N, counts, bcounts);
    main_kernel<<<nblocks, 256, 0, stream>>>(states_x, x_target, mol, counts,
                                             partials, N);
    final_kernel<<<1, 256, 0, stream>>>(partials, bcounts, nblocks,
                                        (float*)d_out);
}

// Round 7
// 61.162 us; speedup vs baseline: 4.9324x; 1.1696x over previous
//
#include <hip/hip_runtime.h>

#define GAMMA 0.7f
static constexpr int K = 8;
static constexpr int P = 1024;  // atoms per block (256 threads x 4)

// ---------------------------------------------------------------------------
// 2-launch pipeline. molecule_id is SORTED, so per-atom molecule counts are
// computed INSIDE main_fused from the block's own LDS window (10-step LDS
// binary search); only runs crossing the block edge do a global binary
// search (few lanes, hidden under streaming). No count pre-pass, no zeroing,
// no atomics, no device-scope fences (R2 lesson: per-block __threadfence
// was a 4x regression).
// ws: [0, nblocks*K*4) partials | [boff, +nblocks*4) bcounts. Both fully
// overwritten every call.
// ---------------------------------------------------------------------------

__global__ void __launch_bounds__(256)
main_fused(const float* __restrict__ sx,      // (K, N, 3)
           const float* __restrict__ xt,      // (N, 3)
           const int* __restrict__ mol,       // (N,) sorted
           float* __restrict__ partials,      // (nblocks, K)
           int* __restrict__ bcounts,         // (nblocks,)
           int N) {
    const int tid = threadIdx.x;
    const int b0  = blockIdx.x * P;
    const int n0  = b0 + tid * 4;

    // ids[0] = mol[b0-1] (or -1), ids[1..P] = window, ids[P+1] = mol[b0+P]
    // (or INT_MAX). Sentinels: ids are in [0, M) so -1 < all, INT_MAX > all.
    __shared__ int ids[P + 2];
    int* w = ids + 1;

    int myid[4];
    if (n0 + 3 < N) {
        int4 v = *reinterpret_cast<const int4*>(mol + n0);
        myid[0] = v.x; myid[1] = v.y; myid[2] = v.z; myid[3] = v.w;
    } else {
#pragma unroll
        for (int j = 0; j < 4; ++j) {
            int n = n0 + j;
            myid[j] = (n < N) ? mol[n] : 0x7fffffff;
        }
    }
#pragma unroll
    for (int j = 0; j < 4; ++j) w[tid * 4 + j] = myid[j];
    if (tid == 0)   ids[0]     = (b0 == 0) ? -1 : mol[b0 - 1];
    if (tid == 255) ids[P + 1] = (b0 + P >= N) ? 0x7fffffff : mol[b0 + P];
    __syncthreads();

    // ---- per-atom inverse molecule count + run-start (validity) count ----
    float inv[4];
    int nb = 0;
#pragma unroll
    for (int j = 0; j < 4; ++j) {
        const int p  = tid * 4 + j;
        const int id = myid[j];
        const bool valid = (b0 + p < N);
        const int prevv = (j > 0) ? myid[j - 1] : ids[p];  // ids[p] == w[p-1]
        if (valid && prevv != id) ++nb;  // run start -> one distinct molecule
        if (!valid) { inv[j] = 0.0f; continue; }
        if (j > 0 && myid[j - 1] == id) { inv[j] = inv[j - 1]; continue; }

        // local run start: first q in [0,p] with w[q] >= id  (id present at p)
        int lo = 0, hi = p;
        while (lo < hi) { int m = (lo + hi) >> 1; if (w[m] < id) lo = m + 1; else hi = m; }
        const int s = lo;
        // local run end: first q in (p,P) with w[q] > id, else P
        lo = p + 1; hi = P;
        while (lo < hi) { int m = (lo + hi) >> 1; if (w[m] <= id) lo = m + 1; else hi = m; }
        const int e = lo;

        int gstart = b0 + s;
        if (s == 0 && ids[0] == id) {  // run extends left of block
            lo = 0; hi = b0;
            while (lo < hi) { int m = (lo + hi) >> 1; if (mol[m] < id) lo = m + 1; else hi = m; }
            gstart = lo;
        }
        int gend = b0 + e;
        if (e == P && ids[P + 1] == id) {  // run extends right of block
            lo = b0 + P; hi = N;
            while (lo < hi) { int m = (lo + hi) >> 1; if (mol[m] <= id) lo = m + 1; else hi = m; }
            gend = lo;
        }
        inv[j] = 1.0f / (float)(gend - gstart);
    }

    // ---- stream states, accumulate sq * inv ----
    float acc[K];
#pragma unroll
    for (int k = 0; k < K; ++k) acc[k] = 0.0f;

    if (n0 + 3 < N) {
        const float4* tp = reinterpret_cast<const float4*>(xt + (size_t)n0 * 3);
        float4 t0 = tp[0], t1 = tp[1], t2 = tp[2];
        float tg[12] = {t0.x, t0.y, t0.z, t0.w, t1.x, t1.y,
                        t1.z, t1.w, t2.x, t2.y, t2.z, t2.w};
#pragma unroll
        for (int k = 0; k < K; ++k) {
            const float4* sp = reinterpret_cast<const float4*>(
                sx + (size_t)k * N * 3 + (size_t)n0 * 3);
            float4 s0 = sp[0], s1 = sp[1], s2 = sp[2];
            float sv[12] = {s0.x, s0.y, s0.z, s0.w, s1.x, s1.y,
                            s1.z, s1.w, s2.x, s2.y, s2.z, s2.w};
#pragma unroll
            for (int j = 0; j < 4; ++j) {
                float dx = sv[3 * j + 0] - tg[3 * j + 0];
                float dy = sv[3 * j + 1] - tg[3 * j + 1];
                float dz = sv[3 * j + 2] - tg[3 * j + 2];
                acc[k] += (dx * dx + dy * dy + dz * dz) * inv[j];
            }
        }
    } else if (n0 < N) {
        for (int n = n0; n < N; ++n) {
            const int j = n - n0;
            float tx = xt[(size_t)n * 3 + 0];
            float ty = xt[(size_t)n * 3 + 1];
            float tz = xt[(size_t)n * 3 + 2];
#pragma unroll
            for (int k = 0; k < K; ++k) {
                const float* s = sx + (size_t)k * N * 3 + (size_t)n * 3;
                float dx = s[0] - tx, dy = s[1] - ty, dz = s[2] - tz;
                acc[k] += (dx * dx + dy * dy + dz * dz) * inv[j];
            }
        }
    }

    // ---- deterministic block reduce (shuffle + LDS), write partials ----
#pragma unroll
    for (int k = 0; k < K; ++k)
#pragma unroll
        for (int off = 32; off > 0; off >>= 1)
            acc[k] += __shfl_down(acc[k], off, 64);
#pragma unroll
    for (int off = 32; off > 0; off >>= 1) nb += __shfl_down(nb, off, 64);

    __shared__ float lds[4][K];
    __shared__ int   bl[4];
    const int wave = tid >> 6, lane = tid & 63;
    if (lane == 0) {
        bl[wave] = nb;
#pragma unroll
        for (int k = 0; k < K; ++k) lds[wave][k] = acc[k];
    }
    __syncthreads();
    if (tid < K) {
        int k = tid;
        partials[(size_t)blockIdx.x * K + k] =
            lds[0][k] + lds[1][k] + lds[2][k] + lds[3][k];
    }
    if (tid == 0)
        bcounts[blockIdx.x] = bl[0] + bl[1] + bl[2] + bl[3];
}

// One block: reduce per-block partials (nblocks*K floats) and boundary
// counts (nblocks ints). No M-sized scan.
__global__ void __launch_bounds__(256)
final_kernel(const float* __restrict__ partials,
             const int* __restrict__ bcounts, int nblocks,
             float* __restrict__ out) {
    const int t = threadIdx.x;

    int vc = 0;
    for (int i = t; i < nblocks; i += 256) vc += bcounts[i];
#pragma unroll
    for (int off = 32; off > 0; off >>= 1) vc += __shfl_down(vc, off, 64);

    float acc[K];
#pragma unroll
    for (int k = 0; k < K; ++k) acc[k] = 0.0f;
    for (int i = t; i < nblocks; i += 256) {
#pragma unroll
        for (int k = 0; k < K; ++k) acc[k] += partials[(size_t)i * K + k];
    }
#pragma unroll
    for (int k = 0; k < K; ++k)
#pragma unroll
        for (int off = 32; off > 0; off >>= 1)
            acc[k] += __shfl_down(acc[k], off, 64);

    __shared__ int vlds[4];
    __shared__ float plds[4][K];
    const int wave = t >> 6, lane = t & 63;
    if (lane == 0) {
        vlds[wave] = vc;
#pragma unroll
        for (int k = 0; k < K; ++k) plds[wave][k] = acc[k];
    }
    __syncthreads();

    if (t == 0) {
        int V = vlds[0] + vlds[1] + vlds[2] + vlds[3];
        float w[K], wsum = 0.0f, g = 1.0f;
        for (int j = 0; j < K; ++j) {  // w[K-1-j] = GAMMA^j
            w[K - 1 - j] = g;
            wsum += g;
            g *= GAMMA;
        }
        float invV = (V > 0) ? 1.0f / (float)V : 0.0f;
        float res = 0.0f;
#pragma unroll
        for (int k = 0; k < K; ++k) {
            float ps = (plds[0][k] + plds[1][k] + plds[2][k] + plds[3][k]) * invV;
            res += (w[k] / wsum) * ps;
        }
        out[0] = res;
    }
}

extern "C" void kernel_launch(void* const* d_in, const int* in_sizes, int n_in,
                              void* d_out, int out_size, void* d_ws, size_t ws_size,
                              hipStream_t stream) {
    const float* states_x = (const float*)d_in[0];  // (K, N, 3)
    const float* x_target = (const float*)d_in[1];  // (N, 3)
    const int*   mol      = (const int*)d_in[2];    // (N,)

    const int N = in_sizes[2];
    const int nblocks = (N + P - 1) / P;

    char* ws = (char*)d_ws;
    size_t boff = (((size_t)nblocks * K * 4) + 255) & ~(size_t)255;

    float* partials = (float*)ws;
    int*   bcounts  = (int*)(ws + boff);

    main_fused<<<nblocks, 256, 0, stream>>>(states_x, x_target, mol,
                                            partials, bcounts, N);
    final_kernel<<<1, 256, 0, stream>>>(partials, bcounts, nblocks,
                                        (float*)d_out);
}